// Round 14
// baseline (289.647 us; speedup 1.0000x reference)
//
#include <hip/hip_runtime.h>

// BinarizeLinear: out[65536,1024] = x @ sign(W)^T + bias
// Round 14: NO-LDS, NO-BARRIER i8 GEMM. Diagnosis: all prior kernels share a
// per-K-step barrier convoy (all waves ds_read together, then all MFMA
// together; pipes serialize) -> 20-23% MfmaUtil invariant across 11 schedule
// variants (R12 drain-0 == R13 counted ring: exactly null). Fix: operands are
// already frag-linear images in d_ws, so each wave loads its MFMA fragments
// directly global->reg (1KB coalesced bursts, XI L3-resident, WI L2-resident),
// double-buffered in NAMED register sets (rule #20), loads issued a full step
// ahead of use. Zero s_barrier in the loop; waves fully independent.
// Prepasses unchanged (proven absmax 1.75): per-row x quant + sign(W) i8.

typedef __bf16 bf16x8 __attribute__((ext_vector_type(8)));
typedef float  f32x4  __attribute__((ext_vector_type(4)));
typedef int    i32x4  __attribute__((ext_vector_type(4)));
typedef char   i8x16  __attribute__((ext_vector_type(16)));

constexpr int Mdim = 65536, Ndim = 1024, Kdim = 1024;

typedef const __attribute__((address_space(1))) char ga_char;
typedef __attribute__((address_space(3))) char lds_char;
__device__ __forceinline__ void gload16(const void* g, void* l) {
    __builtin_amdgcn_global_load_lds((ga_char*)g, (lds_char*)l, 16, 0, 0);
}
__device__ __forceinline__ f32x4 mfma16(bf16x8 a, bf16x8 b, f32x4 c) {
    return __builtin_amdgcn_mfma_f32_16x16x32_bf16(a, b, c, 0, 0, 0);
}
__device__ __forceinline__ i32x4 mfma_i8(i32x4 a, i32x4 b, i32x4 c) {
    return __builtin_amdgcn_mfma_i32_16x16x64_i8(a, b, c, 0, 0, 0);
}

// =====================  i8 path  =====================

// ---- prepass 1: x -> per-row-scaled i8, frag-linear image (R12 exact) ----
__global__ __launch_bounds__(256)
void xquant_kernel(const float* __restrict__ X, char* __restrict__ XI,
                   float* __restrict__ SC) {
    const int lane = threadIdx.x & 63;
    const int row  = blockIdx.x * 4 + (threadIdx.x >> 6);
    const float* src = X + (size_t)row * Kdim + lane * 16;
    f32x4 v[4];
#pragma unroll
    for (int k = 0; k < 4; ++k) v[k] = *(const f32x4*)(src + k * 4);
    float m = 0.f;
#pragma unroll
    for (int k = 0; k < 4; ++k)
#pragma unroll
        for (int e = 0; e < 4; ++e) m = fmaxf(m, fabsf(v[k][e]));
#pragma unroll
    for (int i = 1; i < 64; i <<= 1) m = fmaxf(m, __shfl_xor(m, i));
    const float s = (m > 0.f) ? 127.f / m : 0.f;
    i8x16 o;
#pragma unroll
    for (int k = 0; k < 4; ++k)
#pragma unroll
        for (int e = 0; e < 4; ++e)
            o[k * 4 + e] = (char)__float2int_rn(v[k][e] * s);
    const int rowb = row >> 7, mb = (row >> 4) & 7, fr = row & 15;
    const int kt = lane >> 2, hq = lane & 3;
    *(i8x16*)(XI + (size_t)(rowb * 16 + kt) * 8192 + mb * 1024
              + (hq * 16 + fr) * 16) = o;
    if (lane == 0) SC[row] = m * (1.f / 127.f);
}

// ---- prepass 2: sign(W) -> i8 frag-linear image (R12 exact) ----
__global__ __launch_bounds__(256)
void wsign8_kernel(const float* __restrict__ W, char* __restrict__ WI) {
    const int id   = blockIdx.x * 256 + threadIdx.x;   // 65536 threads
    const int lane = id & 63;
    const int nb   = (id >> 6) & 15;
    const int kt   = (id >> 10) & 15;
    const int colb = id >> 14;                          // 0..3
    const float* src = W + (size_t)(colb * 256 + nb * 16 + (lane & 15)) * Kdim
                         + kt * 64 + (lane >> 4) * 16;
    i8x16 o;
#pragma unroll
    for (int k = 0; k < 4; ++k) {
        f32x4 v = *(const f32x4*)(src + k * 4);
#pragma unroll
        for (int e = 0; e < 4; ++e)
            o[k * 4 + e] = (char)((v[e] > 0.f) - (v[e] < 0.f));
    }
    *(i8x16*)(WI + (size_t)id * 16) = o;
}

// ---- main GEMM: no LDS, no barriers, reg-double-buffered frags ----
__global__ __launch_bounds__(512)
void binlin_i8nl(const char* __restrict__ XI, const char* __restrict__ WI,
                 const float* __restrict__ SC, const float* __restrict__ bias,
                 float* __restrict__ out)
{
    constexpr int NWG = (Mdim / 128) * (Ndim / 256);   // 2048
    const int swz  = (blockIdx.x & 7) * (NWG / 8) + (blockIdx.x >> 3);
    const int colb = swz & 3;
    const int rowb = swz >> 2;
    const int row0 = rowb * 128;

    const int tid  = threadIdx.x;
    const int lane = tid & 63;
    const int wid  = tid >> 6;
    const int wr   = wid >> 2;        // M half (64 rows)
    const int wcn  = wid & 3;         // N quarter (64 cols)
    const int fr   = lane & 15;
    const int hq   = lane >> 4;

    // per-wave fragment base pointers (1KB coalesced per frag load)
    const char* Ab = XI + (size_t)rowb * 16 * 8192 + (wr * 4) * 1024 + lane * 16;
    const char* Bb = WI + (size_t)colb * 16 * 16384 + (wcn * 4) * 1024 + lane * 16;

    i32x4 acc[4][4] = {};
    i32x4 a0[4], b0[4], a1[4], b1[4];   // named double-buffer sets (rule #20)

#define LOADSET(As, Bs, kt) do {                                              \
    _Pragma("unroll")                                                         \
    for (int i = 0; i < 4; ++i)                                               \
        As[i] = *(const i32x4*)(Ab + (size_t)(kt) * 8192 + i * 1024);         \
    _Pragma("unroll")                                                         \
    for (int j = 0; j < 4; ++j)                                               \
        Bs[j] = *(const i32x4*)(Bb + (size_t)(kt) * 16384 + j * 1024);        \
} while (0)

#define MFMASET(As, Bs) do {                                                  \
    _Pragma("unroll")                                                         \
    for (int j = 0; j < 4; ++j)                                               \
        _Pragma("unroll")                                                     \
        for (int i = 0; i < 4; ++i)                                           \
            acc[i][j] = mfma_i8(As[i], Bs[j], acc[i][j]);                     \
} while (0)

    constexpr int NKT = Kdim / 64;    // 16 (even)
    LOADSET(a0, b0, 0);
    for (int t = 0; t < NKT; t += 2) {
        LOADSET(a1, b1, t + 1);       // issue a full step before use
        MFMASET(a0, b0);              // waitcnt auto-counted for set0 only
        if (t + 2 < NKT) LOADSET(a0, b0, t + 2);
        MFMASET(a1, b1);
    }
#undef LOADSET
#undef MFMASET

    // epilogue: row = orow + i*16 + r, col = ocol + j*16; per-row dequant
    const int orow = row0 + wr * 64 + hq * 4;
    const int ocol = colb * 256 + wcn * 64 + fr;
    f32x4 sv[4];
#pragma unroll
    for (int i = 0; i < 4; ++i) sv[i] = *(const f32x4*)(SC + orow + i * 16);
#pragma unroll
    for (int j = 0; j < 4; ++j) {
        const float bv = bias[ocol + j * 16];
#pragma unroll
        for (int i = 0; i < 4; ++i)
#pragma unroll
            for (int r = 0; r < 4; ++r)
                out[(size_t)(orow + i * 16 + r) * Ndim + (ocol + j * 16)] =
                    (float)acc[i][j][r] * sv[i][r] + bv;
    }
}

// =====================  bf16 fallback paths (R12 exact)  =====================

__global__ __launch_bounds__(256)
void wprep_kernel(const float* __restrict__ W, __bf16* __restrict__ WS) {
    const int id   = blockIdx.x * 256 + threadIdx.x;   // 131072
    const int colb = id >> 15;
    const int kt   = (id >> 10) & 31;
    const int g    = id & 1023;
    const int nb   = g >> 6;
    const int lane = g & 63;
    const int row  = colb * 256 + nb * 16 + (lane & 15);
    const int col  = kt * 32 + (lane >> 4) * 8;
    const float* src = W + (size_t)row * Kdim + col;
    f32x4 a = *(const f32x4*)src;
    f32x4 b = *(const f32x4*)(src + 4);
    bf16x8 o;
#pragma unroll
    for (int e = 0; e < 4; ++e) {
        o[e]     = (__bf16)(float)((a[e] > 0.f) - (a[e] < 0.f));
        o[e + 4] = (__bf16)(float)((b[e] > 0.f) - (b[e] < 0.f));
    }
    *(bf16x8*)(WS + (size_t)id * 8) = o;
}

__global__ __launch_bounds__(512, 4)
void binlin128x256(const float* __restrict__ X, const __bf16* __restrict__ WS,
                   const float* __restrict__ bias, float* __restrict__ out)
{
    __shared__ __align__(16) char Alc[2][128 * 80];
    __shared__ __align__(16) __bf16 Bl[2][256 * 32];
    constexpr int mNWG = (Mdim / 128) * (Ndim / 256);
    const int swz  = (blockIdx.x & 7) * (mNWG / 8) + (blockIdx.x >> 3);
    const int colb = swz & 3;
    const int rowb = swz >> 2;
    const int row0 = rowb * 128;
    const int tid  = threadIdx.x;
    const int lane = tid & 63;
    const int wid  = tid >> 6;
    const int wr   = wid >> 2;
    const int wcn  = wid & 3;
    const int fr   = lane & 15;
    const int hq   = lane >> 4;
    const int a_r  = tid >> 2;
    const int a_c  = (tid & 3) * 8;
    const float* Xb = X + (size_t)(row0 + a_r) * Kdim + a_c;
    const __bf16* WSb = WS + (size_t)colb * 262144;
    f32x4 ra[2];
    auto GLA = [&](int kt) {
        const float* p = Xb + kt * 32;
        ra[0] = *(const f32x4*)p;
        ra[1] = *(const f32x4*)(p + 4);
    };
    auto DSWA = [&](int buf) {
        bf16x8 v;
#pragma unroll
        for (int e = 0; e < 4; ++e) {
            v[e] = (__bf16)ra[0][e]; v[e + 4] = (__bf16)ra[1][e];
        }
        *(bf16x8*)(&Alc[buf][a_r * 80 + a_c * 2]) = v;
    };
    auto GLB = [&](int buf, int kt) {
        const __bf16* s = WSb + (size_t)kt * 8192 + wid * 1024 + lane * 8;
        gload16(s,       &Bl[buf][wid * 1024]);
        gload16(s + 512, &Bl[buf][wid * 1024 + 512]);
    };
    auto lda = [&](int buf, int i) -> bf16x8 {
        const int row = wr * 64 + i * 16 + fr;
        return *(const bf16x8*)(&Alc[buf][row * 80 + hq * 16]);
    };
    auto ldb = [&](int buf, int j) -> bf16x8 {
        return *(const bf16x8*)(&Bl[buf][(wcn * 4 + j) * 512 + lane * 8]);
    };
    f32x4 acc[4][4] = {};
    GLA(0); GLB(0, 0); DSWA(0);
    __syncthreads();
    int cur = 0;
    for (int t = 0; t < 32; ++t) {
        const int nxt = cur ^ 1;
        const bool pre = (t + 1 < 32);
        if (pre) { GLA(t + 1); GLB(nxt, t + 1); }
        bf16x8 af[4];
#pragma unroll
        for (int i = 0; i < 4; ++i) af[i] = lda(cur, i);
        __builtin_amdgcn_s_setprio(1);
#pragma unroll
        for (int j = 0; j < 4; ++j) {
            bf16x8 bfr = ldb(cur, j);
#pragma unroll
            for (int i = 0; i < 4; ++i)
                acc[i][j] = mfma16(af[i], bfr, acc[i][j]);
        }
        __builtin_amdgcn_s_setprio(0);
        if (pre) { DSWA(nxt); __syncthreads(); }
        cur = nxt;
    }
    const int orow = row0 + wr * 64 + hq * 4;
    const int ocol = colb * 256 + wcn * 64 + fr;
#pragma unroll
    for (int j = 0; j < 4; ++j) {
        const float bv = bias[ocol + j * 16];
#pragma unroll
        for (int i = 0; i < 4; ++i)
#pragma unroll
            for (int r = 0; r < 4; ++r)
                out[(size_t)(orow + i * 16 + r) * Ndim + (ocol + j * 16)] =
                    acc[i][j][r] + bv;
    }
}

__global__ __launch_bounds__(256)
void binlin_fallback(const float* __restrict__ X, const float* __restrict__ Wf,
                     const float* __restrict__ bias, float* __restrict__ out)
{
    __shared__ __align__(16) __bf16 Al[2][128][32];
    __shared__ __align__(16) __bf16 Bl[2][128][32];
    const int swz  = (blockIdx.x & 7) * (4096 / 8) + (blockIdx.x >> 3);
    const int colb = swz & 7, rowb = swz >> 3;
    const int row0 = rowb * 128, col0 = colb * 128;
    const int tid = threadIdx.x, lane = tid & 63, wid = tid >> 6;
    const int wr = wid >> 1, wc = wid & 1;
    const int sr = tid >> 2, sc = (tid & 3) * 8;
    const float* Xb = X + (size_t)row0 * Kdim;
    const float* Wb = Wf + (size_t)col0 * Kdim;
    f32x4 ra[2][2], rb[2][2];
    auto GL = [&](int k0) {
#pragma unroll
        for (int p = 0; p < 2; ++p) {
            const float* sa = Xb + (size_t)(p * 64 + sr) * Kdim + k0 + sc;
            ra[p][0] = *(const f32x4*)sa; ra[p][1] = *(const f32x4*)(sa + 4);
            const float* sb = Wb + (size_t)(p * 64 + sr) * Kdim + k0 + sc;
            rb[p][0] = *(const f32x4*)sb; rb[p][1] = *(const f32x4*)(sb + 4);
        }
    };
    auto DSW = [&](int buf) {
#pragma unroll
        for (int p = 0; p < 2; ++p) {
            bf16x8 va, vb;
#pragma unroll
            for (int e = 0; e < 4; ++e) {
                va[e] = (__bf16)ra[p][0][e]; va[e + 4] = (__bf16)ra[p][1][e];
                float a = rb[p][0][e], b = rb[p][1][e];
                vb[e] = (__bf16)(float)((a > 0.f) - (a < 0.f));
                vb[e + 4] = (__bf16)(float)((b > 0.f) - (b < 0.f));
            }
            *(bf16x8*)&Al[buf][p * 64 + sr][sc] = va;
            *(bf16x8*)&Bl[buf][p * 64 + sr][sc] = vb;
        }
    };
    f32x4 acc[4][4] = {};
    const int fr = lane & 15, ks = (lane >> 4) * 8;
    auto COMP = [&](int buf) {
        bf16x8 af[4], bf[4];
#pragma unroll
        for (int i = 0; i < 4; ++i) af[i] = *(const bf16x8*)&Al[buf][wr * 64 + fr + i * 16][ks];
#pragma unroll
        for (int j = 0; j < 4; ++j) bf[j] = *(const bf16x8*)&Bl[buf][wc * 64 + fr + j * 16][ks];
#pragma unroll
        for (int i = 0; i < 4; ++i)
#pragma unroll
            for (int j = 0; j < 4; ++j)
                acc[i][j] = mfma16(af[i], bf[j], acc[i][j]);
    };
    GL(0); DSW(0); __syncthreads();
    int cur = 0;
    for (int t = 0; t < 32; ++t) {
        if (t + 1 < 32) GL((t + 1) * 32);
        COMP(cur);
        if (t + 1 < 32) { DSW(cur ^ 1); __syncthreads(); cur ^= 1; }
    }
    const int orow = row0 + wr * 64 + (lane >> 4) * 4;
    const int ocol = col0 + wc * 64 + fr;
#pragma unroll
    for (int j = 0; j < 4; ++j) {
        const float bv = bias[ocol + j * 16];
#pragma unroll
        for (int i = 0; i < 4; ++i)
#pragma unroll
            for (int r = 0; r < 4; ++r)
                out[(size_t)(orow + i * 16 + r) * Ndim + (ocol + j * 16)] = acc[i][j][r] + bv;
    }
}

extern "C" void kernel_launch(void* const* d_in, const int* in_sizes, int n_in,
                              void* d_out, int out_size, void* d_ws, size_t ws_size,
                              hipStream_t stream) {
    const float* x  = (const float*)d_in[0];
    const float* w  = (const float*)d_in[1];
    const float* b  = (const float*)d_in[2];
    float* out      = (float*)d_out;

    constexpr size_t WI_BYTES = (size_t)Ndim * Kdim;            // 1 MB (i8)
    constexpr size_t SC_BYTES = (size_t)Mdim * sizeof(float);   // 256 KB
    constexpr size_t XI_BYTES = (size_t)Mdim * Kdim;            // 64 MB (i8)
    constexpr size_t I8_TOTAL = WI_BYTES + SC_BYTES + XI_BYTES; // ~65.3 MB
    constexpr size_t WS_BYTES = (size_t)Ndim * Kdim * sizeof(__bf16); // 2 MB

    if (ws_size >= I8_TOTAL) {
        char*  wi = (char*)d_ws;
        float* sc = (float*)((char*)d_ws + WI_BYTES);
        char*  xi = (char*)d_ws + WI_BYTES + SC_BYTES;
        wsign8_kernel<<<dim3(256),   dim3(256), 0, stream>>>(w, wi);
        xquant_kernel<<<dim3(16384), dim3(256), 0, stream>>>(x, xi, sc);
        binlin_i8nl<<<dim3(2048), dim3(512), 0, stream>>>(xi, wi, sc, b, out);
    } else if (ws_size >= WS_BYTES) {
        __bf16* ws = (__bf16*)d_ws;
        wprep_kernel<<<dim3(512), dim3(256), 0, stream>>>(w, ws);
        binlin128x256<<<dim3(2048), dim3(512), 0, stream>>>(x, ws, b, out);
    } else {
        binlin_fallback<<<dim3(4096), dim3(256), 0, stream>>>(x, w, b, out);
    }
}

// Round 15
// 223.233 us; speedup vs baseline: 1.2975x; 1.2975x over previous
//
#include <hip/hip_runtime.h>

// BinarizeLinear: out[65536,1024] = x @ sign(W)^T + bias
// Round 15: R12 structure + 32x32x32 i8 MFMA (half the MFMA instructions,
// 2x pipe occupancy each, +12% ubench rate) to attack the issue-rate wall
// (R12 drain-0 == R13 counted == null; latency & LDS-BW & HBM all ruled out;
// matrix pipe needs 653 of ~2900 cyc/block-step -> feed-starved).
// Image layouts re-derived for 32x32 frags: A row=lane&31,k=(lane>>5)*16;
// B col=lane&31,k=(lane>>5)*16; C/D col=lane&31,row=(reg&3)+8(reg>>2)+
// 4(lane>>5) [m101-verified]. Loop/staging/tile EXACTLY R12 (proven best):
// BM=128 BN=256 BK=64, 8 waves, 2-phase gload_lds double-buffer, 2 blocks/CU.

typedef __bf16 bf16x8 __attribute__((ext_vector_type(8)));
typedef float  f32x4  __attribute__((ext_vector_type(4)));
typedef int    i32x4  __attribute__((ext_vector_type(4)));
typedef int    i32x16 __attribute__((ext_vector_type(16)));
typedef char   i8x16  __attribute__((ext_vector_type(16)));

constexpr int Mdim = 65536, Ndim = 1024, Kdim = 1024;

typedef const __attribute__((address_space(1))) char ga_char;
typedef __attribute__((address_space(3))) char lds_char;
__device__ __forceinline__ void gload16(const void* g, void* l) {
    __builtin_amdgcn_global_load_lds((ga_char*)g, (lds_char*)l, 16, 0, 0);
}
__device__ __forceinline__ f32x4 mfma16(bf16x8 a, bf16x8 b, f32x4 c) {
    return __builtin_amdgcn_mfma_f32_16x16x32_bf16(a, b, c, 0, 0, 0);
}

// =====================  i8 / 32x32 path  =====================

// ---- prepass 1: x -> per-row i8, 32x32-frag-linear image ----
// One wave per row r; lane l owns k in [16l, 16l+16).
// tile (r>>7)*16 + (l>>2) [8KB]; unit u = ((r>>5)&3)*2 + ((l>>1)&1);
// frag-lane L = (l&1)*32 + (r&31); byte = tile*8192 + u*1024 + L*16.
__global__ __launch_bounds__(256)
void xquant32_kernel(const float* __restrict__ X, char* __restrict__ XI,
                     float* __restrict__ SC) {
    const int l   = threadIdx.x & 63;
    const int row = blockIdx.x * 4 + (threadIdx.x >> 6);
    const float* src = X + (size_t)row * Kdim + l * 16;
    f32x4 v[4];
#pragma unroll
    for (int k = 0; k < 4; ++k) v[k] = *(const f32x4*)(src + k * 4);
    float m = 0.f;
#pragma unroll
    for (int k = 0; k < 4; ++k)
#pragma unroll
        for (int e = 0; e < 4; ++e) m = fmaxf(m, fabsf(v[k][e]));
#pragma unroll
    for (int i = 1; i < 64; i <<= 1) m = fmaxf(m, __shfl_xor(m, i));
    const float s = (m > 0.f) ? 127.f / m : 0.f;
    i8x16 o;
#pragma unroll
    for (int k = 0; k < 4; ++k)
#pragma unroll
        for (int e = 0; e < 4; ++e)
            o[k * 4 + e] = (char)__float2int_rn(v[k][e] * s);
    const size_t tile = (size_t)(row >> 7) * 16 + (l >> 2);
    const int u  = (((row >> 5) & 3) << 1) | ((l >> 1) & 1);
    const int L  = ((l & 1) << 5) | (row & 31);
    *(i8x16*)(XI + tile * 8192 + u * 1024 + L * 16) = o;
    if (l == 0) SC[row] = m * (1.f / 127.f);
}

// ---- prepass 2: sign(W) -> i8, 32x32-frag-linear image (1MB) ----
// One wave per W row n (output col). tile (n>>8)*16 + (l>>2) [16KB];
// unit u = ((n>>5)&7)*2 + ((l>>1)&1); L = (l&1)*32 + (n&31).
__global__ __launch_bounds__(256)
void wsign32_kernel(const float* __restrict__ W, char* __restrict__ WI) {
    const int l = threadIdx.x & 63;
    const int n = blockIdx.x * 4 + (threadIdx.x >> 6);
    const float* src = W + (size_t)n * Kdim + l * 16;
    i8x16 o;
#pragma unroll
    for (int k = 0; k < 4; ++k) {
        f32x4 v = *(const f32x4*)(src + k * 4);
#pragma unroll
        for (int e = 0; e < 4; ++e)
            o[k * 4 + e] = (char)((v[e] > 0.f) - (v[e] < 0.f));
    }
    const size_t tile = (size_t)(n >> 8) * 16 + (l >> 2);
    const int u  = (((n >> 5) & 7) << 1) | ((l >> 1) & 1);
    const int L  = ((l & 1) << 5) | (n & 31);
    *(i8x16*)(WI + tile * 16384 + u * 1024 + L * 16) = o;
}

// ---- main GEMM: 32x32x32 i8, R12 loop structure ----
__global__ __launch_bounds__(512, 4)
void binlin_i8w32(const char* __restrict__ XI, const char* __restrict__ WI,
                  const float* __restrict__ SC, const float* __restrict__ bias,
                  float* __restrict__ out)
{
    __shared__ __align__(16) char Al[2][8192];    // 128x64 i8
    __shared__ __align__(16) char Bl[2][16384];   // 256x64 i8

    constexpr int NWG = (Mdim / 128) * (Ndim / 256);   // 2048
    const int swz  = (blockIdx.x & 7) * (NWG / 8) + (blockIdx.x >> 3);
    const int colb = swz & 3;
    const int rowb = swz >> 2;

    const int tid  = threadIdx.x;
    const int lane = tid & 63;
    const int wid  = tid >> 6;
    const int wr   = wid >> 2;        // M half (64 rows = 2 row-blocks of 32)
    const int wcn  = wid & 3;         // N quarter (64 cols = 2 col-blocks)
    const int l31  = lane & 31;
    const int h    = lane >> 5;       // 0..1

    const char* XIb = XI + (size_t)rowb * 16 * 8192;
    const char* WIb = WI + (size_t)colb * 16 * 16384;

    auto STAGE = [&](int buf, int kt) {   // layout-agnostic byte copy (R12)
        gload16(XIb + (size_t)kt * 8192 + tid * 16, &Al[buf][tid * 16]);
        const char* bsrc = WIb + (size_t)kt * 16384 + tid * 16;
        gload16(bsrc,        &Bl[buf][tid * 16]);
        gload16(bsrc + 8192, &Bl[buf][8192 + tid * 16]);
    };
    // A unit u = rb*2 + kb (rb = wr*2 + ii); B unit u = cb*2 + kb (cb = wcn*2 + jj)
    auto lda = [&](int buf, int ii, int kb) -> i32x4 {
        return *(const i32x4*)(&Al[buf][(((wr * 2 + ii) << 1) | kb) * 1024 + lane * 16]);
    };
    auto ldb = [&](int buf, int jj, int kb) -> i32x4 {
        return *(const i32x4*)(&Bl[buf][(((wcn * 2 + jj) << 1) | kb) * 1024 + lane * 16]);
    };

    i32x16 acc[2][2] = {};

    STAGE(0, 0);
    __syncthreads();

    constexpr int NKT = Kdim / 64;    // 16
    int cur = 0;
    for (int t = 0; t < NKT; ++t) {
        const int nxt = cur ^ 1;
        const bool pre = (t + 1 < NKT);
        if (pre) STAGE(nxt, t + 1);   // in flight during COMP

        i32x4 a[2][2], b[2][2];
#pragma unroll
        for (int kb = 0; kb < 2; ++kb)
#pragma unroll
            for (int q = 0; q < 2; ++q) {
                a[kb][q] = lda(cur, q, kb);
                b[kb][q] = ldb(cur, q, kb);
            }
        __builtin_amdgcn_s_setprio(1);
#pragma unroll
        for (int kb = 0; kb < 2; ++kb)
#pragma unroll
            for (int ii = 0; ii < 2; ++ii)
#pragma unroll
                for (int jj = 0; jj < 2; ++jj)
                    acc[ii][jj] = __builtin_amdgcn_mfma_i32_32x32x32_i8(
                        a[kb][ii], b[kb][jj], acc[ii][jj], 0, 0, 0);
        __builtin_amdgcn_s_setprio(0);

        if (pre) __syncthreads();
        cur = nxt;
    }

    // epilogue: C 32x32 frag: col = l31, row = (r&3) + 8*(r>>2) + 4*h
    // per (ii,jj): orow = rowb*128 + wr*64 + ii*32; ocol = ...+ jj*32 + l31
#pragma unroll
    for (int ii = 0; ii < 2; ++ii) {
        const int orow = rowb * 128 + wr * 64 + ii * 32 + h * 4;
        f32x4 sv[4];
#pragma unroll
        for (int q = 0; q < 4; ++q) sv[q] = *(const f32x4*)(SC + orow + q * 8);
#pragma unroll
        for (int jj = 0; jj < 2; ++jj) {
            const int ocol = colb * 256 + wcn * 64 + jj * 32 + l31;
            const float bv = bias[ocol];
#pragma unroll
            for (int q = 0; q < 4; ++q)
#pragma unroll
                for (int e = 0; e < 4; ++e)
                    out[(size_t)(orow + q * 8 + e) * Ndim + ocol] =
                        (float)acc[ii][jj][q * 4 + e] * sv[q][e] + bv;
        }
    }
}

// =====================  bf16 fallback paths  =====================

__global__ __launch_bounds__(256)
void wprep_kernel(const float* __restrict__ W, __bf16* __restrict__ WS) {
    const int id   = blockIdx.x * 256 + threadIdx.x;   // 131072
    const int colb = id >> 15;
    const int kt   = (id >> 10) & 31;
    const int g    = id & 1023;
    const int nb   = g >> 6;
    const int lane = g & 63;
    const int row  = colb * 256 + nb * 16 + (lane & 15);
    const int col  = kt * 32 + (lane >> 4) * 8;
    const float* src = W + (size_t)row * Kdim + col;
    f32x4 a = *(const f32x4*)src;
    f32x4 b = *(const f32x4*)(src + 4);
    bf16x8 o;
#pragma unroll
    for (int e = 0; e < 4; ++e) {
        o[e]     = (__bf16)(float)((a[e] > 0.f) - (a[e] < 0.f));
        o[e + 4] = (__bf16)(float)((b[e] > 0.f) - (b[e] < 0.f));
    }
    *(bf16x8*)(WS + (size_t)id * 8) = o;
}

__global__ __launch_bounds__(512, 4)
void binlin128x256(const float* __restrict__ X, const __bf16* __restrict__ WS,
                   const float* __restrict__ bias, float* __restrict__ out)
{
    __shared__ __align__(16) char Alc[2][128 * 80];
    __shared__ __align__(16) __bf16 Bl[2][256 * 32];
    constexpr int mNWG = (Mdim / 128) * (Ndim / 256);
    const int swz  = (blockIdx.x & 7) * (mNWG / 8) + (blockIdx.x >> 3);
    const int colb = swz & 3;
    const int rowb = swz >> 2;
    const int row0 = rowb * 128;
    const int tid  = threadIdx.x;
    const int lane = tid & 63;
    const int wid  = tid >> 6;
    const int wr   = wid >> 2;
    const int wcn  = wid & 3;
    const int fr   = lane & 15;
    const int hq   = lane >> 4;
    const int a_r  = tid >> 2;
    const int a_c  = (tid & 3) * 8;
    const float* Xb = X + (size_t)(row0 + a_r) * Kdim + a_c;
    const __bf16* WSb = WS + (size_t)colb * 262144;
    f32x4 ra[2];
    auto GLA = [&](int kt) {
        const float* p = Xb + kt * 32;
        ra[0] = *(const f32x4*)p;
        ra[1] = *(const f32x4*)(p + 4);
    };
    auto DSWA = [&](int buf) {
        bf16x8 v;
#pragma unroll
        for (int e = 0; e < 4; ++e) {
            v[e] = (__bf16)ra[0][e]; v[e + 4] = (__bf16)ra[1][e];
        }
        *(bf16x8*)(&Alc[buf][a_r * 80 + a_c * 2]) = v;
    };
    auto GLB = [&](int buf, int kt) {
        const __bf16* s = WSb + (size_t)kt * 8192 + wid * 1024 + lane * 8;
        gload16(s,       &Bl[buf][wid * 1024]);
        gload16(s + 512, &Bl[buf][wid * 1024 + 512]);
    };
    auto lda = [&](int buf, int i) -> bf16x8 {
        const int row = wr * 64 + i * 16 + fr;
        return *(const bf16x8*)(&Alc[buf][row * 80 + hq * 16]);
    };
    auto ldb = [&](int buf, int j) -> bf16x8 {
        return *(const bf16x8*)(&Bl[buf][(wcn * 4 + j) * 512 + lane * 8]);
    };
    f32x4 acc[4][4] = {};
    GLA(0); GLB(0, 0); DSWA(0);
    __syncthreads();
    int cur = 0;
    for (int t = 0; t < 32; ++t) {
        const int nxt = cur ^ 1;
        const bool pre = (t + 1 < 32);
        if (pre) { GLA(t + 1); GLB(nxt, t + 1); }
        bf16x8 af[4];
#pragma unroll
        for (int i = 0; i < 4; ++i) af[i] = lda(cur, i);
        __builtin_amdgcn_s_setprio(1);
#pragma unroll
        for (int j = 0; j < 4; ++j) {
            bf16x8 bfr = ldb(cur, j);
#pragma unroll
            for (int i = 0; i < 4; ++i)
                acc[i][j] = mfma16(af[i], bfr, acc[i][j]);
        }
        __builtin_amdgcn_s_setprio(0);
        if (pre) { DSWA(nxt); __syncthreads(); }
        cur = nxt;
    }
    const int orow = row0 + wr * 64 + hq * 4;
    const int ocol = colb * 256 + wcn * 64 + fr;
#pragma unroll
    for (int j = 0; j < 4; ++j) {
        const float bv = bias[ocol + j * 16];
#pragma unroll
        for (int i = 0; i < 4; ++i)
#pragma unroll
            for (int r = 0; r < 4; ++r)
                out[(size_t)(orow + i * 16 + r) * Ndim + (ocol + j * 16)] =
                    acc[i][j][r] + bv;
    }
}

__global__ __launch_bounds__(256)
void binlin_fallback(const float* __restrict__ X, const float* __restrict__ Wf,
                     const float* __restrict__ bias, float* __restrict__ out)
{
    __shared__ __align__(16) __bf16 Al[2][128][32];
    __shared__ __align__(16) __bf16 Bl[2][128][32];
    const int swz  = (blockIdx.x & 7) * (4096 / 8) + (blockIdx.x >> 3);
    const int colb = swz & 7, rowb = swz >> 3;
    const int row0 = rowb * 128, col0 = colb * 128;
    const int tid = threadIdx.x, lane = tid & 63, wid = tid >> 6;
    const int wr = wid >> 1, wc = wid & 1;
    const int sr = tid >> 2, sc = (tid & 3) * 8;
    const float* Xb = X + (size_t)row0 * Kdim;
    const float* Wb = Wf + (size_t)col0 * Kdim;
    f32x4 ra[2][2], rb[2][2];
    auto GL = [&](int k0) {
#pragma unroll
        for (int p = 0; p < 2; ++p) {
            const float* sa = Xb + (size_t)(p * 64 + sr) * Kdim + k0 + sc;
            ra[p][0] = *(const f32x4*)sa; ra[p][1] = *(const f32x4*)(sa + 4);
            const float* sb = Wb + (size_t)(p * 64 + sr) * Kdim + k0 + sc;
            rb[p][0] = *(const f32x4*)sb; rb[p][1] = *(const f32x4*)(sb + 4);
        }
    };
    auto DSW = [&](int buf) {
#pragma unroll
        for (int p = 0; p < 2; ++p) {
            bf16x8 va, vb;
#pragma unroll
            for (int e = 0; e < 4; ++e) {
                va[e] = (__bf16)ra[p][0][e]; va[e + 4] = (__bf16)ra[p][1][e];
                float a = rb[p][0][e], b = rb[p][1][e];
                vb[e] = (__bf16)(float)((a > 0.f) - (a < 0.f));
                vb[e + 4] = (__bf16)(float)((b > 0.f) - (b < 0.f));
            }
            *(bf16x8*)&Al[buf][p * 64 + sr][sc] = va;
            *(bf16x8*)&Bl[buf][p * 64 + sr][sc] = vb;
        }
    };
    f32x4 acc[4][4] = {};
    const int fr = lane & 15, ks = (lane >> 4) * 8;
    auto COMP = [&](int buf) {
        bf16x8 af[4], bf[4];
#pragma unroll
        for (int i = 0; i < 4; ++i) af[i] = *(const bf16x8*)&Al[buf][wr * 64 + fr + i * 16][ks];
#pragma unroll
        for (int j = 0; j < 4; ++j) bf[j] = *(const bf16x8*)&Bl[buf][wc * 64 + fr + j * 16][ks];
#pragma unroll
        for (int i = 0; i < 4; ++i)
#pragma unroll
            for (int j = 0; j < 4; ++j)
                acc[i][j] = mfma16(af[i], bf[j], acc[i][j]);
    };
    GL(0); DSW(0); __syncthreads();
    int cur = 0;
    for (int t = 0; t < 32; ++t) {
        if (t + 1 < 32) GL((t + 1) * 32);
        COMP(cur);
        if (t + 1 < 32) { DSW(cur ^ 1); __syncthreads(); cur ^= 1; }
    }
    const int orow = row0 + wr * 64 + (lane >> 4) * 4;
    const int ocol = col0 + wc * 64 + fr;
#pragma unroll
    for (int j = 0; j < 4; ++j) {
        const float bv = bias[ocol + j * 16];
#pragma unroll
        for (int i = 0; i < 4; ++i)
#pragma unroll
            for (int r = 0; r < 4; ++r)
                out[(size_t)(orow + i * 16 + r) * Ndim + (ocol + j * 16)] = acc[i][j][r] + bv;
    }
}

extern "C" void kernel_launch(void* const* d_in, const int* in_sizes, int n_in,
                              void* d_out, int out_size, void* d_ws, size_t ws_size,
                              hipStream_t stream) {
    const float* x  = (const float*)d_in[0];
    const float* w  = (const float*)d_in[1];
    const float* b  = (const float*)d_in[2];
    float* out      = (float*)d_out;

    constexpr size_t WI_BYTES = (size_t)Ndim * Kdim;            // 1 MB (i8)
    constexpr size_t SC_BYTES = (size_t)Mdim * sizeof(float);   // 256 KB
    constexpr size_t XI_BYTES = (size_t)Mdim * Kdim;            // 64 MB (i8)
    constexpr size_t I8_TOTAL = WI_BYTES + SC_BYTES + XI_BYTES; // ~65.3 MB
    constexpr size_t WS_BYTES = (size_t)Ndim * Kdim * sizeof(__bf16); // 2 MB

    if (ws_size >= I8_TOTAL) {
        char*  wi = (char*)d_ws;
        float* sc = (float*)((char*)d_ws + WI_BYTES);
        char*  xi = (char*)d_ws + WI_BYTES + SC_BYTES;
        wsign32_kernel<<<dim3(256),   dim3(256), 0, stream>>>(w, wi);
        xquant32_kernel<<<dim3(16384), dim3(256), 0, stream>>>(x, xi, sc);
        binlin_i8w32<<<dim3(2048), dim3(512), 0, stream>>>(xi, wi, sc, b, out);
    } else if (ws_size >= WS_BYTES) {
        __bf16* ws = (__bf16*)d_ws;
        wprep_kernel<<<dim3(512), dim3(256), 0, stream>>>(w, ws);
        binlin128x256<<<dim3(2048), dim3(512), 0, stream>>>(x, ws, b, out);
    } else {
        binlin_fallback<<<dim3(4096), dim3(256), 0, stream>>>(x, w, b, out);
    }
}